// Round 1
// baseline (989.602 us; speedup 1.0000x reference)
//
#include <hip/hip_runtime.h>

#define N_NODES 100000
#define N_EDGES 3200000
#define IN_DIM  512
#define HID_DIM 16

__device__ __forceinline__ void atomic_add_f32(float* p, float v) {
    __hip_atomic_fetch_add(p, v, __ATOMIC_RELAXED, __HIP_MEMORY_SCOPE_AGENT);
}

// k0: zero h, out = b2, build W1T (transposed W1 for vectorized loads in k1)
__global__ void k0_init(const float* __restrict__ W1, const float* __restrict__ b2,
                        float* __restrict__ W1T, float* __restrict__ h,
                        float* __restrict__ out) {
    int i = blockIdx.x * blockDim.x + threadIdx.x;
    if (i < N_NODES * HID_DIM) h[i] = 0.0f;
    if (i < N_NODES) out[i] = b2[0];
    if (i < IN_DIM * HID_DIM) {
        int j = i & (HID_DIM - 1);   // col
        int k = i >> 4;              // row
        W1T[j * IN_DIM + k] = W1[i];
    }
}

// k1: xw[row][j] = dot(x[row, :], W1[:, j]); thread owns (row, j-pair)
// x reads: 8 distinct float4 per wave (8 rows), W1T reads: L1-resident 32 KB.
__global__ void k1_xw(const float4* __restrict__ x4, const float4* __restrict__ w1t4,
                      float2* __restrict__ xw2) {
    int t = blockIdx.x * blockDim.x + threadIdx.x;   // t < N_NODES*8
    int j2  = t & 7;
    int row = t >> 3;
    const float4* __restrict__ xr = x4   + (size_t)row * (IN_DIM / 4);
    const float4* __restrict__ wa = w1t4 + (size_t)(2 * j2)     * (IN_DIM / 4);
    const float4* __restrict__ wb = w1t4 + (size_t)(2 * j2 + 1) * (IN_DIM / 4);
    float a0 = 0.0f, a1 = 0.0f;
    #pragma unroll 8
    for (int k = 0; k < IN_DIM / 4; ++k) {
        float4 xv = xr[k];
        float4 w0 = wa[k];
        float4 w1 = wb[k];
        a0 += xv.x * w0.x + xv.y * w0.y + xv.z * w0.z + xv.w * w0.w;
        a1 += xv.x * w1.x + xv.y * w1.y + xv.z * w1.z + xv.w * w1.w;
    }
    xw2[(size_t)row * 8 + j2] = make_float2(a0, a1);
}

// k2: h[dst][j] += w_e * xw[src][j]; one thread per (edge, j)
// 16 consecutive j-lanes share edge data (L1 broadcast) and make the
// gather/atomic addresses 64B-contiguous per edge.
__global__ void k2_spmm1(const int* __restrict__ src, const int* __restrict__ dst,
                         const float* __restrict__ wgt, const float* __restrict__ xw,
                         float* __restrict__ h) {
    int t = blockIdx.x * blockDim.x + threadIdx.x;   // t < N_EDGES*16
    int e = t >> 4;
    int j = t & (HID_DIM - 1);
    if (e < N_EDGES) {
        int s = src[e], d = dst[e];
        float v = wgt[e] * xw[(size_t)s * HID_DIM + j];
        atomic_add_f32(&h[(size_t)d * HID_DIM + j], v);
    }
}

// k3: hw[i] = relu(h[i] + b1) . W2
__global__ void k3_act(const float* __restrict__ h, const float* __restrict__ b1,
                       const float* __restrict__ W2, float* __restrict__ hw) {
    int i = blockIdx.x * blockDim.x + threadIdx.x;
    if (i >= N_NODES) return;
    const float4* __restrict__ h4 = (const float4*)(h + (size_t)i * HID_DIM);
    const float4* __restrict__ b4 = (const float4*)b1;
    const float4* __restrict__ w4 = (const float4*)W2;
    float acc = 0.0f;
    #pragma unroll
    for (int q = 0; q < HID_DIM / 4; ++q) {
        float4 hv = h4[q];
        float4 bv = b4[q];
        float4 wv = w4[q];
        acc += fmaxf(hv.x + bv.x, 0.0f) * wv.x;
        acc += fmaxf(hv.y + bv.y, 0.0f) * wv.y;
        acc += fmaxf(hv.z + bv.z, 0.0f) * wv.z;
        acc += fmaxf(hv.w + bv.w, 0.0f) * wv.w;
    }
    hw[i] = acc;
}

// k4: out[dst] += w_e * hw[src]; one thread per edge
__global__ void k4_spmm2(const int* __restrict__ src, const int* __restrict__ dst,
                         const float* __restrict__ wgt, const float* __restrict__ hw,
                         float* __restrict__ out) {
    int e = blockIdx.x * blockDim.x + threadIdx.x;
    if (e < N_EDGES) {
        atomic_add_f32(&out[dst[e]], wgt[e] * hw[src[e]]);
    }
}

extern "C" void kernel_launch(void* const* d_in, const int* in_sizes, int n_in,
                              void* d_out, int out_size, void* d_ws, size_t ws_size,
                              hipStream_t stream) {
    const float* x    = (const float*)d_in[0];
    const int*   esrc = (const int*)  d_in[1];
    const int*   edst = (const int*)  d_in[2];
    const float* ew   = (const float*)d_in[3];
    const float* W1   = (const float*)d_in[4];
    const float* b1   = (const float*)d_in[5];
    const float* W2   = (const float*)d_in[6];
    const float* b2   = (const float*)d_in[7];
    float* out = (float*)d_out;

    float* ws  = (float*)d_ws;
    float* xw  = ws;                                   // N*16 floats
    float* h   = xw + (size_t)N_NODES * HID_DIM;       // N*16 floats
    float* hw  = h  + (size_t)N_NODES * HID_DIM;       // N floats
    float* W1T = hw + N_NODES;                         // 512*16 floats

    // k0: init h=0, out=b2, W1T
    {
        int n = N_NODES * HID_DIM;
        k0_init<<<(n + 255) / 256, 256, 0, stream>>>(W1, b2, W1T, h, out);
    }
    // k1: xw = x @ W1
    k1_xw<<<(N_NODES * 8) / 256, 256, 0, stream>>>(
        (const float4*)x, (const float4*)W1T, (float2*)xw);
    // k2: h += scatter(w * xw[src]) by dst
    k2_spmm1<<<(N_EDGES * 16) / 256, 256, 0, stream>>>(esrc, edst, ew, xw, h);
    // k3: hw = relu(h + b1) @ W2
    k3_act<<<(N_NODES + 255) / 256, 256, 0, stream>>>(h, b1, W2, hw);
    // k4: out += scatter(w * hw[src]) by dst
    k4_spmm2<<<(N_EDGES + 255) / 256, 256, 0, stream>>>(esrc, edst, ew, hw, out);
}